// Round 7
// baseline (379.156 us; speedup 1.0000x reference)
//
#include <hip/hip_runtime.h>
#include <hip/hip_fp16.h>
#include <math.h>

// RPMNet registration, fused persistent kernel, linear-domain Sinkhorn with
// REGISTER-RESIDENT fp16 K. B=16, N=1024, feat 6; 3 reg iters x 5 sk iters.
// R13: BARRIER-FREE DATAFLOW SYNC. The per-phase cross-block reduce no longer
// uses a spin barrier (drain + arrive + detect, ~3 MALL round trips). Each
// column of Sv is ONE u64: high bits = contribution counter, low 48 bits =
// fixed-point (2^-32) value. A block's contribution is a single u64 atomicAdd
// of (1<<48)+fix(s); a consumer polls until (u>>48)==16 — at which point the
// low bits ARE the complete sum (counter and data become visible atomically
// together; no flag/data race, no vmcnt drain, no barrier). The 3 moment-
// accumulator phases use the same scheme with a sign bias (counter at bit 52,
// bias 2^44, scale 2^-20). Fixed point is MORE precise than fp32 atomics and
// bit-identical across the redundant per-block SVDs. One block-local
// __syncthreads per phase protects LDS svp reuse. Skeleton (512-thr blocks,
// 16 blocks/batch, grid 256, agent-scope ops, adjacent-column K packing,
// batched reloads) is R12-proven at 269us.
//
// ws (u32 words): [0..1023]  accum u64[3][16][16]  ((it,b) slice = one 128B line)
//                 [2048..]   Sv u64[15][16][1024]
//                 all prep-zeroed each launch; PREP_FLOATS = 493568 = 1928*256

#define BATCH 16
#define NPTS  1024
#define REG_ITERS 3
#define SK_ITERS  5
#define EPS 1e-5f
#define LOG2E 1.44269504088896f

#define BLOCK_T   512
#define BLK_PER_B 16          // blocks per batch
#define NWAVES    8           // waves per block

#define WS_ACC64  0           // u64 index
#define WS_SV64   1024        // u64 index (word 2048)
#define SV_STRIDE (BATCH * NPTS)
#define PREP_FLOATS 493568    // 2048 + 15*16*1024*2 u32 words = 1928*256

#define MASK48  0x0000FFFFFFFFFFFFull
#define MASK52  0x000FFFFFFFFFFFFFull
#define SV_SCALE   4294967296.0        // 2^32
#define SV_INV     (1.0 / 4294967296.0)
#define ACC_SCALE  1048576.0           // 2^20
#define ACC_INV    (1.0 / 1048576.0)
#define ACC_BIAS   17592186044416ll    // 2^44
#define ACC_BIAS16 281474976710656.0   // 16 * 2^44 = 2^48

__device__ __forceinline__ unsigned long long ld_coh64(const unsigned long long* p) {
    return __hip_atomic_load((unsigned long long*)p, __ATOMIC_RELAXED,
                             __HIP_MEMORY_SCOPE_AGENT);
}
__device__ __forceinline__ void add_coh64(unsigned long long* p, unsigned long long v) {
    __hip_atomic_fetch_add(p, v, __ATOMIC_RELAXED, __HIP_MEMORY_SCOPE_AGENT);
}

// dataflow Sv read: poll 16 u64s (8 adjacent pairs) until every counter==16,
// then decode fixed-point values. Producers' single-atomic publish guarantees
// counter==16 implies the value bits are the complete 16-block sum.
#define LOAD_WV(sb64)                                                         \
    {                                                                         \
        unsigned long long ga[8], gb[8];                                      \
        for (;;) {                                                            \
            _Pragma("unroll")                                                 \
            for (int j = 0; j < 8; ++j) {                                     \
                ga[j] = ld_coh64((sb64) + 2*lane + 128*j);                    \
                gb[j] = ld_coh64((sb64) + 2*lane + 128*j + 1);                \
            }                                                                 \
            bool rdy = true;                                                  \
            _Pragma("unroll")                                                 \
            for (int j = 0; j < 8; ++j)                                       \
                rdy = rdy && ((ga[j] >> 48) == 16ull)                         \
                          && ((gb[j] >> 48) == 16ull);                        \
            if (__all(rdy)) break;                                            \
            __builtin_amdgcn_s_sleep(1);                                      \
        }                                                                     \
        _Pragma("unroll")                                                     \
        for (int j = 0; j < 8; ++j) {                                         \
            wv0[j] = __builtin_amdgcn_rcpf(                                   \
                1.f + (float)((double)(ga[j] & MASK48) * SV_INV));            \
            wv1[j] = __builtin_amdgcn_rcpf(                                   \
                1.f + (float)((double)(gb[j] & MASK48) * SV_INV));            \
        }                                                                     \
    }

// weighted Kabsch from 16 accum moments + old T -> new T (12 floats)
__device__ void kabsch_svd(const float* ac, const float* Told, float* Tnew) {
    double Sw = ac[0];
    double Sa[3] = {ac[1], ac[2], ac[3]};
    double Sb[3] = {ac[4], ac[5], ac[6]};
    double D  = Sw + (double)EPS;
    double ca0 = Sa[0]/D, ca1 = Sa[1]/D, ca2 = Sa[2]/D;
    double cb0 = Sb[0]/D, cb1 = Sb[1]/D, cb2 = Sb[2]/D;
    double f  = (2.0 - Sw / D) / D;
    double Am[3][3];
    for (int m = 0; m < 3; ++m)
        for (int n = 0; n < 3; ++n)
            Am[m][n] = (double)ac[7 + m*3 + n] - f * Sa[m] * Sb[n];
    double S[3][3];
    for (int i = 0; i < 3; ++i)
        for (int j = 0; j < 3; ++j) {
            double a2 = 0;
            for (int m = 0; m < 3; ++m) a2 += Am[m][i] * Am[m][j];
            S[i][j] = a2;
        }
    double V[3][3] = {{1,0,0},{0,1,0},{0,0,1}};
    const int prr[3] = {0,0,1}, qrr[3] = {1,2,2};
    for (int sweep = 0; sweep < 25; ++sweep) {
        double off = S[0][1]*S[0][1] + S[0][2]*S[0][2] + S[1][2]*S[1][2];
        if (off < 1e-28) break;
        for (int pi = 0; pi < 3; ++pi) {
            int p = prr[pi], q = qrr[pi];
            double apq = S[p][q];
            if (fabs(apq) < 1e-300) continue;
            double theta = (S[q][q] - S[p][p]) / (2.0 * apq);
            double tt = ((theta >= 0) ? 1.0 : -1.0) / (fabs(theta) + sqrt(theta*theta + 1.0));
            double cth = 1.0 / sqrt(tt*tt + 1.0), sth = tt * cth;
            for (int m = 0; m < 3; ++m) { double a1=S[m][p], a2=S[m][q]; S[m][p]=cth*a1-sth*a2; S[m][q]=sth*a1+cth*a2; }
            for (int m = 0; m < 3; ++m) { double a1=S[p][m], a2=S[q][m]; S[p][m]=cth*a1-sth*a2; S[q][m]=sth*a1+cth*a2; }
            for (int m = 0; m < 3; ++m) { double a1=V[m][p], a2=V[m][q]; V[m][p]=cth*a1-sth*a2; V[m][q]=sth*a1+cth*a2; }
        }
    }
    double lam[3] = {S[0][0], S[1][1], S[2][2]};
    int idx[3] = {0,1,2};
    if (lam[idx[0]] < lam[idx[1]]) { int t2=idx[0]; idx[0]=idx[1]; idx[1]=t2; }
    if (lam[idx[0]] < lam[idx[2]]) { int t2=idx[0]; idx[0]=idx[2]; idx[2]=t2; }
    if (lam[idx[1]] < lam[idx[2]]) { int t2=idx[1]; idx[1]=idx[2]; idx[2]=t2; }
    double Vs[3][3], sv[3];
    for (int i = 0; i < 3; ++i) {
        int c = idx[i];
        for (int m = 0; m < 3; ++m) Vs[m][i] = V[m][c];
        double l = lam[c]; sv[i] = sqrt(l > 0 ? l : 0);
    }
    double Us[3][3] = {{1,0,0},{0,1,0},{0,0,1}};
    double smax = sv[0] > 1e-300 ? sv[0] : 1e-300;
    for (int i = 0; i < 3; ++i) {
        double ux = Am[0][0]*Vs[0][i] + Am[0][1]*Vs[1][i] + Am[0][2]*Vs[2][i];
        double uy = Am[1][0]*Vs[0][i] + Am[1][1]*Vs[1][i] + Am[1][2]*Vs[2][i];
        double uz = Am[2][0]*Vs[0][i] + Am[2][1]*Vs[1][i] + Am[2][2]*Vs[2][i];
        if (sv[i] > 1e-12 * smax) {
            Us[0][i] = ux/sv[i]; Us[1][i] = uy/sv[i]; Us[2][i] = uz/sv[i];
        } else if (i == 2) {
            double cx = Us[1][0]*Us[2][1] - Us[2][0]*Us[1][1];
            double cy = Us[2][0]*Us[0][1] - Us[0][0]*Us[2][1];
            double cz = Us[0][0]*Us[1][1] - Us[1][0]*Us[0][1];
            double n = sqrt(cx*cx + cy*cy + cz*cz); n = n > 1e-300 ? n : 1.0;
            Us[0][i] = cx/n; Us[1][i] = cy/n; Us[2][i] = cz/n;
        }
    }
    double M[3][3];
    for (int m = 0; m < 3; ++m)
        for (int n = 0; n < 3; ++n)
            M[m][n] = Vs[m][0]*Us[n][0] + Vs[m][1]*Us[n][1] + Vs[m][2]*Us[n][2];
    double det = M[0][0]*(M[1][1]*M[2][2]-M[1][2]*M[2][1])
               - M[0][1]*(M[1][0]*M[2][2]-M[1][2]*M[2][0])
               + M[0][2]*(M[1][0]*M[2][1]-M[1][1]*M[2][0]);
    double g3 = (det > 0.0) ? 1.0 : -1.0;
    double R[3][3];
    for (int m = 0; m < 3; ++m)
        for (int n = 0; n < 3; ++n)
            R[m][n] = Vs[m][0]*Us[n][0] + Vs[m][1]*Us[n][1] + g3*Vs[m][2]*Us[n][2];
    double ti[3];
    ti[0] = -(R[0][0]*ca0 + R[0][1]*ca1 + R[0][2]*ca2) + cb0;
    ti[1] = -(R[1][0]*ca0 + R[1][1]*ca1 + R[1][2]*ca2) + cb1;
    ti[2] = -(R[2][0]*ca0 + R[2][1]*ca1 + R[2][2]*ca2) + cb2;
    double Ro[3][3] = {{Told[0],Told[1],Told[2]},{Told[4],Told[5],Told[6]},{Told[8],Told[9],Told[10]}};
    double to[3] = {Told[3], Told[7], Told[11]};
    for (int m = 0; m < 3; ++m) {
        for (int n = 0; n < 3; ++n)
            Tnew[m*4+n] = (float)(R[m][0]*Ro[0][n] + R[m][1]*Ro[1][n] + R[m][2]*Ro[2][n]);
        Tnew[m*4+3] = (float)(R[m][0]*to[0] + R[m][1]*to[1] + R[m][2]*to[2] + ti[m]);
    }
}

__global__ __launch_bounds__(256) void prep_kernel(float* ws) {
    int i = blockIdx.x * 256 + threadIdx.x;   // grid 1928 x 256
    ws[i] = 0.f;
}

__global__
__attribute__((amdgpu_flat_work_group_size(BLOCK_T, BLOCK_T), amdgpu_waves_per_eu(2, 2)))
void rpm_kernel(
        const float* __restrict__ psrc, const float* __restrict__ pref,
        const float* __restrict__ beta, const float* __restrict__ alpha,
        float* __restrict__ ws, float* __restrict__ outT, float* __restrict__ perm)
{
    __shared__ float refL[NPTS * 7];          // 28 KB: x,y,z,f3,f4,f5,sq (stride 7)
    __shared__ float svp[NWAVES][NPTS];       // 32 KB: per-wave column partials
    __shared__ float sred[NWAVES][16];
    __shared__ float tT[12];
    __shared__ float tTn[12];

    const int blk = blockIdx.x, b = blk & 15, sub = blk >> 4;
    const int tid = threadIdx.x, wid = tid >> 6, lane = tid & 63;
    const int rbase = (sub << 6) + (wid << 3);                  // 64 rows/block
    const int grow  = (b << 10) + rbase;

    unsigned long long* acc64 = (unsigned long long*)ws + WS_ACC64;
    unsigned long long* sv64  = (unsigned long long*)ws + WS_SV64;

    const float bet2 = beta[b] * LOG2E;
    const float alp  = alpha[b];
    const float tb2  = 2.f * bet2;

    // ---- stage ref features to LDS (block-local)
    for (int i = tid; i < NPTS; i += BLOCK_T) {
        const float* p = pref + ((size_t)(b << 10) + i) * 6;
        float x=p[0], y=p[1], z=p[2], aa=p[3], bb=p[4], cc=p[5];
        float* o = refL + i * 7;
        o[0]=x; o[1]=y; o[2]=z; o[3]=aa; o[4]=bb; o[5]=cc;
        o[6] = x*x + y*y + z*z + aa*aa + bb*bb + cc*cc;
    }
    if (tid < 12) tT[tid] = (tid == 0 || tid == 5 || tid == 10) ? 1.f : 0.f;
    __syncthreads();

    // Kh[r][j] holds ADJACENT columns (2*lane + 128*j, +1) packed fp16x2.
    __half2 Kh[8][8];
    float wu[8];

    for (int it = 0; it < REG_ITERS; ++it) {
        const bool last = (it == REG_ITERS - 1);

        // ---- A) K-build: transform own rows, K = exp2(aff2) -> fp16 registers
        {
            float rx[8], ry[8], rz[8], f3[8], f4[8], f5[8], cr[8];
            #pragma unroll
            for (int r = 0; r < 8; ++r) {
                const float* p = psrc + (size_t)(grow + r) * 6;
                float x = p[0], y = p[1], z = p[2];
                float tx = tT[0]*x + tT[1]*y + tT[2]*z  + tT[3];
                float ty = tT[4]*x + tT[5]*y + tT[6]*z  + tT[7];
                float tz = tT[8]*x + tT[9]*y + tT[10]*z + tT[11];
                f3[r] = p[3]; f4[r] = p[4]; f5[r] = p[5];
                rx[r] = tx; ry[r] = ty; rz[r] = tz;
                float sq = tx*tx + ty*ty + tz*tz + f3[r]*f3[r] + f4[r]*f4[r] + f5[r]*f5[r];
                cr[r] = bet2 * (alp - sq);
            }
            #pragma unroll
            for (int j = 0; j < 8; ++j) {
                const float* L0 = refL + (2*lane + 128*j) * 7;
                const float* L1 = L0 + 7;
                float a0=L0[0], a1=L0[1], a2=L0[2], a3=L0[3], a4=L0[4], a5=L0[5];
                float c0=L1[0], c1=L1[1], c2=L1[2], c3=L1[3], c4=L1[4], c5=L1[5];
                float tk0 = bet2 * L0[6], tk1 = bet2 * L1[6];
                #pragma unroll
                for (int r = 0; r < 8; ++r) {
                    float d0 = rx[r]*a0 + ry[r]*a1 + rz[r]*a2 + f3[r]*a3 + f4[r]*a4 + f5[r]*a5;
                    float d1 = rx[r]*c0 + ry[r]*c1 + rz[r]*c2 + f3[r]*c3 + f4[r]*c4 + f5[r]*c5;
                    float k0 = __builtin_amdgcn_exp2f(fmaf(tb2, d0, cr[r] - tk0));
                    float k1 = __builtin_amdgcn_exp2f(fmaf(tb2, d1, cr[r] - tk1));
                    Kh[r][j] = __floats2half2_rn(k0, k1);
                }
            }
        }

        // ---- B) 5 x (u-pass local, v-pass -> LDS pre-reduce -> u64 Sv add)
        for (int sk = 0; sk < SK_ITERS; ++sk) {
            float Su[8];
            #pragma unroll
            for (int r = 0; r < 8; ++r) Su[r] = 0.f;
            if (sk == 0) {
                #pragma unroll
                for (int j = 0; j < 8; ++j)
                    #pragma unroll
                    for (int r = 0; r < 8; ++r) {
                        float2 kk = __half22float2(Kh[r][j]);
                        Su[r] += kk.x + kk.y;
                    }
            } else {
                const unsigned long long* sb = sv64
                    + (size_t)(it*SK_ITERS + sk - 1) * SV_STRIDE + (b << 10);
                float wv0[8], wv1[8];
                LOAD_WV(sb);
                #pragma unroll
                for (int j = 0; j < 8; ++j)
                    #pragma unroll
                    for (int r = 0; r < 8; ++r) {
                        float2 kk = __half22float2(Kh[r][j]);
                        Su[r] = fmaf(kk.x, wv0[j], fmaf(kk.y, wv1[j], Su[r]));
                    }
            }
            #pragma unroll
            for (int r = 0; r < 8; ++r) {
                float a = Su[r];
                for (int off = 32; off; off >>= 1) a += __shfl_down(a, off);
                wu[r] = __builtin_amdgcn_rcpf(1.f + __shfl(a, 0));
            }
            // v-pass: per-wave column partials -> LDS -> cross-wave reduce ->
            // single u64 atomic per column per block (counter+value packed)
            #pragma unroll
            for (int j = 0; j < 8; ++j) {
                float p0 = 0.f, p1 = 0.f;
                #pragma unroll
                for (int r = 0; r < 8; ++r) {
                    float2 kk = __half22float2(Kh[r][j]);
                    p0 = fmaf(kk.x, wu[r], p0);
                    p1 = fmaf(kk.y, wu[r], p1);
                }
                svp[wid][2*lane + 128*j]     = p0;
                svp[wid][2*lane + 128*j + 1] = p1;
            }
            __syncthreads();
            unsigned long long* vb = sv64
                + (size_t)(it*SK_ITERS + sk) * SV_STRIDE + (b << 10);
            #pragma unroll
            for (int c0 = 0; c0 < 2; ++c0) {
                int c = tid + BLOCK_T*c0;
                float s = svp[0][c] + svp[1][c] + svp[2][c] + svp[3][c]
                        + svp[4][c] + svp[5][c] + svp[6][c] + svp[7][c];
                unsigned long long contrib = (1ull << 48)
                    + (unsigned long long)((double)s * SV_SCALE + 0.5);
                add_coh64(vb + c, contrib);
            }
            __syncthreads();   // svp reuse guard (replaces old barrier's sync)
        }

        // ---- C) finalize: perm (last iter) + moment accumulators
        {
            const unsigned long long* sb = sv64
                + (size_t)(it*SK_ITERS + SK_ITERS - 1) * SV_STRIDE + (b << 10);
            float wv0[8], wv1[8];
            LOAD_WV(sb);
            // recompute transformed src coords (freed from registers during sinkhorn)
            float rx[8], ry[8], rz[8];
            #pragma unroll
            for (int r = 0; r < 8; ++r) {
                const float* p = psrc + (size_t)(grow + r) * 6;
                float x = p[0], y = p[1], z = p[2];
                rx[r] = tT[0]*x + tT[1]*y + tT[2]*z  + tT[3];
                ry[r] = tT[4]*x + tT[5]*y + tT[6]*z  + tT[7];
                rz[r] = tT[8]*x + tT[9]*y + tT[10]*z + tT[11];
            }
            float pS[16];
            #pragma unroll
            for (int i2 = 0; i2 < 16; ++i2) pS[i2] = 0.f;
            for (int r = 0; r < 8; ++r) {
                float s=0.f, smx=0.f, smy=0.f, smz=0.f;
                const float w = wu[r];
                #pragma unroll
                for (int j = 0; j < 8; ++j) {
                    int k0 = 2*lane + 128*j;
                    float2 kk = __half22float2(Kh[r][j]);
                    float p0 = kk.x * w * wv0[j];
                    float p1 = kk.y * w * wv1[j];
                    const float* L0 = refL + k0 * 7;
                    const float* L1 = L0 + 7;
                    s += p0 + p1;
                    smx += p0*L0[0] + p1*L1[0];
                    smy += p0*L0[1] + p1*L1[1];
                    smz += p0*L0[2] + p1*L1[2];
                    if (last) {
                        __builtin_nontemporal_store(p0, &perm[(size_t)(grow + r) * NPTS + k0]);
                        __builtin_nontemporal_store(p1, &perm[(size_t)(grow + r) * NPTS + k0 + 1]);
                    }
                }
                for (int off = 32; off; off >>= 1) {
                    s   += __shfl_down(s,   off);
                    smx += __shfl_down(smx, off);
                    smy += __shfl_down(smy, off);
                    smz += __shfl_down(smz, off);
                }
                if (lane == 0) {
                    float inv = 1.f / (s + EPS);
                    float bx = smx*inv, by = smy*inv, bz = smz*inv;
                    float fx = rx[r], fy = ry[r], fz = rz[r];
                    pS[0] += s;
                    pS[1] += s*fx;  pS[2] += s*fy;  pS[3] += s*fz;
                    pS[4] += s*bx;  pS[5] += s*by;  pS[6] += s*bz;
                    pS[7] += s*fx*bx;  pS[8]  += s*fx*by;  pS[9]  += s*fx*bz;
                    pS[10]+= s*fy*bx;  pS[11] += s*fy*by;  pS[12] += s*fy*bz;
                    pS[13]+= s*fz*bx;  pS[14] += s*fz*by;  pS[15] += s*fz*bz;
                }
            }
            if (lane == 0) {
                #pragma unroll
                for (int i2 = 0; i2 < 16; ++i2) sred[wid][i2] = pS[i2];
            }
            __syncthreads();
            unsigned long long* ac = acc64 + (it * 16 + b) * 16;  // one 128B line
            if (tid < 16) {
                float s = sred[0][tid] + sred[1][tid] + sred[2][tid] + sred[3][tid]
                        + sred[4][tid] + sred[5][tid] + sred[6][tid] + sred[7][tid];
                double sv = (double)s * ACC_SCALE;
                long long fx = (long long)(sv + (sv >= 0.0 ? 0.5 : -0.5));
                unsigned long long contrib = (1ull << 52)
                    + (unsigned long long)(fx + ACC_BIAS);
                add_coh64(ac + tid, contrib);
            }
            // dataflow accum readback: spin until all 16 contributions landed
            if (!last || sub == 0) {
                if (tid < 16) {
                    unsigned long long u;
                    for (;;) {
                        u = ld_coh64(ac + tid);
                        if ((u >> 52) == 16ull) break;
                        __builtin_amdgcn_s_sleep(1);
                    }
                    sred[0][tid] = (float)(((double)(u & MASK52) - ACC_BIAS16) * ACC_INV);
                }
                __syncthreads();
                if (tid == 0) {
                    float acl[16];
                    #pragma unroll
                    for (int i2 = 0; i2 < 16; ++i2) acl[i2] = sred[0][i2];
                    float Tl[12];
                    #pragma unroll
                    for (int i2 = 0; i2 < 12; ++i2) Tl[i2] = tT[i2];
                    kabsch_svd(acl, Tl, tTn);
                }
                __syncthreads();
                if (tid < 12) tT[tid] = tTn[tid];
                __syncthreads();
                if (last && tid == 0) {
                    #pragma unroll
                    for (int i2 = 0; i2 < 12; ++i2) outT[b * 12 + i2] = tT[i2];
                }
            }
        }
    }
}

extern "C" void kernel_launch(void* const* d_in, const int* in_sizes, int n_in,
                              void* d_out, int out_size, void* d_ws, size_t ws_size,
                              hipStream_t stream) {
    const float* psrc  = (const float*)d_in[0];
    const float* pref  = (const float*)d_in[1];
    const float* beta  = (const float*)d_in[2];
    const float* alpha = (const float*)d_in[3];

    float* out     = (float*)d_out;
    float* outT    = out;            // (16,3,4)
    float* outPerm = out + 192;      // (16,1024,1024)
    float* ws      = (float*)d_ws;

    prep_kernel<<<PREP_FLOATS / 256, 256, 0, stream>>>(ws);

    void* args[] = { (void*)&psrc, (void*)&pref, (void*)&beta, (void*)&alpha,
                     (void*)&ws, (void*)&outT, (void*)&outPerm };
    hipError_t ce = hipLaunchCooperativeKernel((const void*)rpm_kernel,
                                               dim3(BATCH * BLK_PER_B), dim3(BLOCK_T),
                                               args, 0, stream);
    if (ce != hipSuccess) {
        rpm_kernel<<<dim3(BATCH * BLK_PER_B), dim3(BLOCK_T), 0, stream>>>(
            psrc, pref, beta, alpha, ws, outT, outPerm);
    }
}

// Round 8
// 358.240 us; speedup vs baseline: 1.0584x; 1.0584x over previous
//
#include <hip/hip_runtime.h>
#include <hip/hip_fp16.h>
#include <math.h>

// RPMNet registration, fused persistent kernel, linear-domain Sinkhorn with
// REGISTER-RESIDENT fp16 K. B=16, N=1024, feat 6; 3 reg iters x 5 sk iters.
// R14: R12 skeleton (269us proven: 512-thr blocks, 16 blocks/batch, grid 256,
// agent-scope atomics + relaxed spin barrier, adjacent-column K packing,
// batched reloads) + COOPERATIVE LDS BROADCAST of wv = rcp(1+Sv):
// previously EACH of the 8 waves read the full 1024-col Sv slice from the
// MALL and computed all 1024 rcps (8x redundant; ~125MB/launch agent reads =
// the measured 99MB FETCH_SIZE). Now 512 threads load the slice ONCE (8B
// ld_coh2 each), rcp once, stage wv[1024] in 4KB LDS; waves read their 16
// values from LDS (stride-2 = free 2-way bank conflict). R13's u64 dataflow
// sync (all-wave polling) REGRESSED (321us) and is reverted.
//
// ws (floats): [0..767] accum[3][16][16] | [1024..1535 as u32] barriers
//              | [1536..] Sv[15][16][1024]   (all prep-zeroed each launch)

#define BATCH 16
#define NPTS  1024
#define REG_ITERS 3
#define SK_ITERS  5
#define EPS 1e-5f
#define LOG2E 1.44269504088896f

#define BLOCK_T   512
#define BLK_PER_B 16          // blocks per batch
#define NWAVES    8           // waves per block

#define WS_ACC  0
#define WS_BARU 1024
#define WS_SV   1536
#define SV_STRIDE (BATCH * NPTS)
#define PREP_FLOATS (WS_SV + REG_ITERS * SK_ITERS * SV_STRIDE)  // 247296 = 966*256

__device__ __forceinline__ float ld_coh(const float* p) {
    return __hip_atomic_load((float*)p, __ATOMIC_RELAXED, __HIP_MEMORY_SCOPE_AGENT);
}
// 8B relaxed agent-scope load of two adjacent Sv floats (one dwordx2).
__device__ __forceinline__ float2 ld_coh2(const float* p) {
    unsigned long long u = __hip_atomic_load((const unsigned long long*)p,
                                             __ATOMIC_RELAXED, __HIP_MEMORY_SCOPE_AGENT);
    union { unsigned long long u; float2 f; } c; c.u = u; return c.f;
}
__device__ __forceinline__ void add_coh(float* p, float v) {
    __hip_atomic_fetch_add(p, v, __ATOMIC_RELAXED, __HIP_MEMORY_SCOPE_AGENT);
}

// relaxed spin barrier (R1/R12-proven): no acquire/release cache maintenance.
__device__ __forceinline__ void batch_barrier(unsigned* bar, unsigned target) {
    __syncthreads();
    if (threadIdx.x == 0) {
        __builtin_amdgcn_s_waitcnt(0);   // drain my stores/atomics to coherent point
        __hip_atomic_fetch_add(bar, 1u, __ATOMIC_RELAXED, __HIP_MEMORY_SCOPE_AGENT);
        while (__hip_atomic_load(bar, __ATOMIC_RELAXED, __HIP_MEMORY_SCOPE_AGENT) < target)
            __builtin_amdgcn_s_sleep(1);
    }
    __syncthreads();
    __asm__ __volatile__("" ::: "memory");
}

// cooperative Sv broadcast: 512 threads load 1024 cols ONCE (8B each),
// rcp once, stage to LDS; every wave then reads its 16 regs from LDS.
// Caller must be past a barrier/syncthreads since last wvS use (reuse guard).
#define LOAD_WV_COOP(sbp)                                                     \
    {                                                                         \
        float2 gv = ld_coh2((sbp) + 2*tid);                                   \
        wvS[2*tid]     = __builtin_amdgcn_rcpf(1.f + gv.x);                   \
        wvS[2*tid + 1] = __builtin_amdgcn_rcpf(1.f + gv.y);                   \
        __syncthreads();                                                      \
        _Pragma("unroll")                                                     \
        for (int j = 0; j < 8; ++j) {                                         \
            wv0[j] = wvS[2*lane + 128*j];                                     \
            wv1[j] = wvS[2*lane + 128*j + 1];                                 \
        }                                                                     \
    }

// weighted Kabsch from 16 accum moments + old T -> new T (12 floats)
__device__ void kabsch_svd(const float* ac, const float* Told, float* Tnew) {
    double Sw = ac[0];
    double Sa[3] = {ac[1], ac[2], ac[3]};
    double Sb[3] = {ac[4], ac[5], ac[6]};
    double D  = Sw + (double)EPS;
    double ca0 = Sa[0]/D, ca1 = Sa[1]/D, ca2 = Sa[2]/D;
    double cb0 = Sb[0]/D, cb1 = Sb[1]/D, cb2 = Sb[2]/D;
    double f  = (2.0 - Sw / D) / D;
    double Am[3][3];
    for (int m = 0; m < 3; ++m)
        for (int n = 0; n < 3; ++n)
            Am[m][n] = (double)ac[7 + m*3 + n] - f * Sa[m] * Sb[n];
    double S[3][3];
    for (int i = 0; i < 3; ++i)
        for (int j = 0; j < 3; ++j) {
            double a2 = 0;
            for (int m = 0; m < 3; ++m) a2 += Am[m][i] * Am[m][j];
            S[i][j] = a2;
        }
    double V[3][3] = {{1,0,0},{0,1,0},{0,0,1}};
    const int prr[3] = {0,0,1}, qrr[3] = {1,2,2};
    for (int sweep = 0; sweep < 25; ++sweep) {
        double off = S[0][1]*S[0][1] + S[0][2]*S[0][2] + S[1][2]*S[1][2];
        if (off < 1e-28) break;
        for (int pi = 0; pi < 3; ++pi) {
            int p = prr[pi], q = qrr[pi];
            double apq = S[p][q];
            if (fabs(apq) < 1e-300) continue;
            double theta = (S[q][q] - S[p][p]) / (2.0 * apq);
            double tt = ((theta >= 0) ? 1.0 : -1.0) / (fabs(theta) + sqrt(theta*theta + 1.0));
            double cth = 1.0 / sqrt(tt*tt + 1.0), sth = tt * cth;
            for (int m = 0; m < 3; ++m) { double a1=S[m][p], a2=S[m][q]; S[m][p]=cth*a1-sth*a2; S[m][q]=sth*a1+cth*a2; }
            for (int m = 0; m < 3; ++m) { double a1=S[p][m], a2=S[q][m]; S[p][m]=cth*a1-sth*a2; S[q][m]=sth*a1+cth*a2; }
            for (int m = 0; m < 3; ++m) { double a1=V[m][p], a2=V[m][q]; V[m][p]=cth*a1-sth*a2; V[m][q]=sth*a1+cth*a2; }
        }
    }
    double lam[3] = {S[0][0], S[1][1], S[2][2]};
    int idx[3] = {0,1,2};
    if (lam[idx[0]] < lam[idx[1]]) { int t2=idx[0]; idx[0]=idx[1]; idx[1]=t2; }
    if (lam[idx[0]] < lam[idx[2]]) { int t2=idx[0]; idx[0]=idx[2]; idx[2]=t2; }
    if (lam[idx[1]] < lam[idx[2]]) { int t2=idx[1]; idx[1]=idx[2]; idx[2]=t2; }
    double Vs[3][3], sv[3];
    for (int i = 0; i < 3; ++i) {
        int c = idx[i];
        for (int m = 0; m < 3; ++m) Vs[m][i] = V[m][c];
        double l = lam[c]; sv[i] = sqrt(l > 0 ? l : 0);
    }
    double Us[3][3] = {{1,0,0},{0,1,0},{0,0,1}};
    double smax = sv[0] > 1e-300 ? sv[0] : 1e-300;
    for (int i = 0; i < 3; ++i) {
        double ux = Am[0][0]*Vs[0][i] + Am[0][1]*Vs[1][i] + Am[0][2]*Vs[2][i];
        double uy = Am[1][0]*Vs[0][i] + Am[1][1]*Vs[1][i] + Am[1][2]*Vs[2][i];
        double uz = Am[2][0]*Vs[0][i] + Am[2][1]*Vs[1][i] + Am[2][2]*Vs[2][i];
        if (sv[i] > 1e-12 * smax) {
            Us[0][i] = ux/sv[i]; Us[1][i] = uy/sv[i]; Us[2][i] = uz/sv[i];
        } else if (i == 2) {
            double cx = Us[1][0]*Us[2][1] - Us[2][0]*Us[1][1];
            double cy = Us[2][0]*Us[0][1] - Us[0][0]*Us[2][1];
            double cz = Us[0][0]*Us[1][1] - Us[1][0]*Us[0][1];
            double n = sqrt(cx*cx + cy*cy + cz*cz); n = n > 1e-300 ? n : 1.0;
            Us[0][i] = cx/n; Us[1][i] = cy/n; Us[2][i] = cz/n;
        }
    }
    double M[3][3];
    for (int m = 0; m < 3; ++m)
        for (int n = 0; n < 3; ++n)
            M[m][n] = Vs[m][0]*Us[n][0] + Vs[m][1]*Us[n][1] + Vs[m][2]*Us[n][2];
    double det = M[0][0]*(M[1][1]*M[2][2]-M[1][2]*M[2][1])
               - M[0][1]*(M[1][0]*M[2][2]-M[1][2]*M[2][0])
               + M[0][2]*(M[1][0]*M[2][1]-M[1][1]*M[2][0]);
    double g3 = (det > 0.0) ? 1.0 : -1.0;
    double R[3][3];
    for (int m = 0; m < 3; ++m)
        for (int n = 0; n < 3; ++n)
            R[m][n] = Vs[m][0]*Us[n][0] + Vs[m][1]*Us[n][1] + g3*Vs[m][2]*Us[n][2];
    double ti[3];
    ti[0] = -(R[0][0]*ca0 + R[0][1]*ca1 + R[0][2]*ca2) + cb0;
    ti[1] = -(R[1][0]*ca0 + R[1][1]*ca1 + R[1][2]*ca2) + cb1;
    ti[2] = -(R[2][0]*ca0 + R[2][1]*ca1 + R[2][2]*ca2) + cb2;
    double Ro[3][3] = {{Told[0],Told[1],Told[2]},{Told[4],Told[5],Told[6]},{Told[8],Told[9],Told[10]}};
    double to[3] = {Told[3], Told[7], Told[11]};
    for (int m = 0; m < 3; ++m) {
        for (int n = 0; n < 3; ++n)
            Tnew[m*4+n] = (float)(R[m][0]*Ro[0][n] + R[m][1]*Ro[1][n] + R[m][2]*Ro[2][n]);
        Tnew[m*4+3] = (float)(R[m][0]*to[0] + R[m][1]*to[1] + R[m][2]*to[2] + ti[m]);
    }
}

__global__ __launch_bounds__(256) void prep_kernel(float* ws) {
    int i = blockIdx.x * 256 + threadIdx.x;   // grid 966 x 256
    ws[i] = 0.f;
}

__global__
__attribute__((amdgpu_flat_work_group_size(BLOCK_T, BLOCK_T), amdgpu_waves_per_eu(2, 2)))
void rpm_kernel(
        const float* __restrict__ psrc, const float* __restrict__ pref,
        const float* __restrict__ beta, const float* __restrict__ alpha,
        float* __restrict__ ws, float* __restrict__ outT, float* __restrict__ perm)
{
    __shared__ float refL[NPTS * 7];          // 28 KB: x,y,z,f3,f4,f5,sq (stride 7)
    __shared__ float svp[NWAVES][NPTS];       // 32 KB: per-wave column partials
    __shared__ float wvS[NPTS];               // 4 KB: broadcast wv = rcp(1+Sv)
    __shared__ float sred[NWAVES][16];
    __shared__ float tT[12];
    __shared__ float tTn[12];

    const int blk = blockIdx.x, b = blk & 15, sub = blk >> 4;
    const int tid = threadIdx.x, wid = tid >> 6, lane = tid & 63;
    const int rbase = (sub << 6) + (wid << 3);                  // 64 rows/block
    const int grow  = (b << 10) + rbase;

    float*    accA = ws + WS_ACC;
    unsigned* bar  = (unsigned*)ws + WS_BARU + b * 32;
    float*    svA  = ws + WS_SV;
    unsigned  phase = 0;

    const float bet2 = beta[b] * LOG2E;
    const float alp  = alpha[b];
    const float tb2  = 2.f * bet2;

    // ---- stage ref features to LDS (block-local)
    for (int i = tid; i < NPTS; i += BLOCK_T) {
        const float* p = pref + ((size_t)(b << 10) + i) * 6;
        float x=p[0], y=p[1], z=p[2], aa=p[3], bb=p[4], cc=p[5];
        float* o = refL + i * 7;
        o[0]=x; o[1]=y; o[2]=z; o[3]=aa; o[4]=bb; o[5]=cc;
        o[6] = x*x + y*y + z*z + aa*aa + bb*bb + cc*cc;
    }
    if (tid < 12) tT[tid] = (tid == 0 || tid == 5 || tid == 10) ? 1.f : 0.f;
    __syncthreads();

    // Kh[r][j] holds ADJACENT columns (2*lane + 128*j, +1) packed fp16x2.
    __half2 Kh[8][8];
    float wu[8];

    for (int it = 0; it < REG_ITERS; ++it) {
        const bool last = (it == REG_ITERS - 1);

        // ---- A) K-build: transform own rows, K = exp2(aff2) -> fp16 registers
        {
            float rx[8], ry[8], rz[8], f3[8], f4[8], f5[8], cr[8];
            #pragma unroll
            for (int r = 0; r < 8; ++r) {
                const float* p = psrc + (size_t)(grow + r) * 6;
                float x = p[0], y = p[1], z = p[2];
                float tx = tT[0]*x + tT[1]*y + tT[2]*z  + tT[3];
                float ty = tT[4]*x + tT[5]*y + tT[6]*z  + tT[7];
                float tz = tT[8]*x + tT[9]*y + tT[10]*z + tT[11];
                f3[r] = p[3]; f4[r] = p[4]; f5[r] = p[5];
                rx[r] = tx; ry[r] = ty; rz[r] = tz;
                float sq = tx*tx + ty*ty + tz*tz + f3[r]*f3[r] + f4[r]*f4[r] + f5[r]*f5[r];
                cr[r] = bet2 * (alp - sq);
            }
            #pragma unroll
            for (int j = 0; j < 8; ++j) {
                const float* L0 = refL + (2*lane + 128*j) * 7;
                const float* L1 = L0 + 7;
                float a0=L0[0], a1=L0[1], a2=L0[2], a3=L0[3], a4=L0[4], a5=L0[5];
                float c0=L1[0], c1=L1[1], c2=L1[2], c3=L1[3], c4=L1[4], c5=L1[5];
                float tk0 = bet2 * L0[6], tk1 = bet2 * L1[6];
                #pragma unroll
                for (int r = 0; r < 8; ++r) {
                    float d0 = rx[r]*a0 + ry[r]*a1 + rz[r]*a2 + f3[r]*a3 + f4[r]*a4 + f5[r]*a5;
                    float d1 = rx[r]*c0 + ry[r]*c1 + rz[r]*c2 + f3[r]*c3 + f4[r]*c4 + f5[r]*c5;
                    float k0 = __builtin_amdgcn_exp2f(fmaf(tb2, d0, cr[r] - tk0));
                    float k1 = __builtin_amdgcn_exp2f(fmaf(tb2, d1, cr[r] - tk1));
                    Kh[r][j] = __floats2half2_rn(k0, k1);
                }
            }
        }

        // ---- B) 5 x (u-pass local, v-pass -> LDS pre-reduce -> atomic Sv)
        for (int sk = 0; sk < SK_ITERS; ++sk) {
            float Su[8];
            #pragma unroll
            for (int r = 0; r < 8; ++r) Su[r] = 0.f;
            if (sk == 0) {
                #pragma unroll
                for (int j = 0; j < 8; ++j)
                    #pragma unroll
                    for (int r = 0; r < 8; ++r) {
                        float2 kk = __half22float2(Kh[r][j]);
                        Su[r] += kk.x + kk.y;
                    }
            } else {
                const float* sb = svA + (it*SK_ITERS + sk - 1) * SV_STRIDE + (b << 10);
                float wv0[8], wv1[8];
                LOAD_WV_COOP(sb);
                #pragma unroll
                for (int j = 0; j < 8; ++j)
                    #pragma unroll
                    for (int r = 0; r < 8; ++r) {
                        float2 kk = __half22float2(Kh[r][j]);
                        Su[r] = fmaf(kk.x, wv0[j], fmaf(kk.y, wv1[j], Su[r]));
                    }
            }
            #pragma unroll
            for (int r = 0; r < 8; ++r) {
                float a = Su[r];
                for (int off = 32; off; off >>= 1) a += __shfl_down(a, off);
                wu[r] = __builtin_amdgcn_rcpf(1.f + __shfl(a, 0));
            }
            // v-pass: per-wave column partials -> LDS (adjacent pair) ->
            // cross-wave reduce -> one agent atomic per column per block
            #pragma unroll
            for (int j = 0; j < 8; ++j) {
                float p0 = 0.f, p1 = 0.f;
                #pragma unroll
                for (int r = 0; r < 8; ++r) {
                    float2 kk = __half22float2(Kh[r][j]);
                    p0 = fmaf(kk.x, wu[r], p0);
                    p1 = fmaf(kk.y, wu[r], p1);
                }
                svp[wid][2*lane + 128*j]     = p0;
                svp[wid][2*lane + 128*j + 1] = p1;
            }
            __syncthreads();
            float* vb = svA + (it*SK_ITERS + sk) * SV_STRIDE + (b << 10);
            #pragma unroll
            for (int c0 = 0; c0 < 2; ++c0) {
                int c = tid + BLOCK_T*c0;
                float s = svp[0][c] + svp[1][c] + svp[2][c] + svp[3][c]
                        + svp[4][c] + svp[5][c] + svp[6][c] + svp[7][c];
                add_coh(vb + c, s);
            }
            batch_barrier(bar, (unsigned)BLK_PER_B * (++phase));
        }

        // ---- C) finalize: perm (last iter) + moment accumulators
        {
            const float* sb = svA + (it*SK_ITERS + SK_ITERS - 1) * SV_STRIDE + (b << 10);
            float wv0[8], wv1[8];
            LOAD_WV_COOP(sb);
            // recompute transformed src coords (freed from registers during sinkhorn)
            float rx[8], ry[8], rz[8];
            #pragma unroll
            for (int r = 0; r < 8; ++r) {
                const float* p = psrc + (size_t)(grow + r) * 6;
                float x = p[0], y = p[1], z = p[2];
                rx[r] = tT[0]*x + tT[1]*y + tT[2]*z  + tT[3];
                ry[r] = tT[4]*x + tT[5]*y + tT[6]*z  + tT[7];
                rz[r] = tT[8]*x + tT[9]*y + tT[10]*z + tT[11];
            }
            float pS[16];
            #pragma unroll
            for (int i2 = 0; i2 < 16; ++i2) pS[i2] = 0.f;
            for (int r = 0; r < 8; ++r) {
                float s=0.f, smx=0.f, smy=0.f, smz=0.f;
                const float w = wu[r];
                #pragma unroll
                for (int j = 0; j < 8; ++j) {
                    int k0 = 2*lane + 128*j;
                    float2 kk = __half22float2(Kh[r][j]);
                    float p0 = kk.x * w * wv0[j];
                    float p1 = kk.y * w * wv1[j];
                    const float* L0 = refL + k0 * 7;
                    const float* L1 = L0 + 7;
                    s += p0 + p1;
                    smx += p0*L0[0] + p1*L1[0];
                    smy += p0*L0[1] + p1*L1[1];
                    smz += p0*L0[2] + p1*L1[2];
                    if (last) {
                        __builtin_nontemporal_store(p0, &perm[(size_t)(grow + r) * NPTS + k0]);
                        __builtin_nontemporal_store(p1, &perm[(size_t)(grow + r) * NPTS + k0 + 1]);
                    }
                }
                for (int off = 32; off; off >>= 1) {
                    s   += __shfl_down(s,   off);
                    smx += __shfl_down(smx, off);
                    smy += __shfl_down(smy, off);
                    smz += __shfl_down(smz, off);
                }
                if (lane == 0) {
                    float inv = 1.f / (s + EPS);
                    float bx = smx*inv, by = smy*inv, bz = smz*inv;
                    float fx = rx[r], fy = ry[r], fz = rz[r];
                    pS[0] += s;
                    pS[1] += s*fx;  pS[2] += s*fy;  pS[3] += s*fz;
                    pS[4] += s*bx;  pS[5] += s*by;  pS[6] += s*bz;
                    pS[7] += s*fx*bx;  pS[8]  += s*fx*by;  pS[9]  += s*fx*bz;
                    pS[10]+= s*fy*bx;  pS[11] += s*fy*by;  pS[12] += s*fy*bz;
                    pS[13]+= s*fz*bx;  pS[14] += s*fz*by;  pS[15] += s*fz*bz;
                }
            }
            if (lane == 0) {
                #pragma unroll
                for (int i2 = 0; i2 < 16; ++i2) sred[wid][i2] = pS[i2];
            }
            __syncthreads();
            float* ac = accA + it * 256 + b * 16;
            if (tid < 16) {
                float s = sred[0][tid] + sred[1][tid] + sred[2][tid] + sred[3][tid]
                        + sred[4][tid] + sred[5][tid] + sred[6][tid] + sred[7][tid];
                add_coh(&ac[tid], s);
            }
            batch_barrier(bar, (unsigned)BLK_PER_B * (++phase));

            // ---- D) SVD redundantly per block from identical accum bits
            if (!last || sub == 0) {
                if (tid == 0) {
                    float acl[16];
                    #pragma unroll
                    for (int i2 = 0; i2 < 16; ++i2) acl[i2] = ld_coh(&ac[i2]);
                    float Tl[12];
                    #pragma unroll
                    for (int i2 = 0; i2 < 12; ++i2) Tl[i2] = tT[i2];
                    kabsch_svd(acl, Tl, tTn);
                }
                __syncthreads();
                if (tid < 12) tT[tid] = tTn[tid];
                __syncthreads();
                if (last && tid == 0) {
                    #pragma unroll
                    for (int i2 = 0; i2 < 12; ++i2) outT[b * 12 + i2] = tT[i2];
                }
            }
        }
    }
}

extern "C" void kernel_launch(void* const* d_in, const int* in_sizes, int n_in,
                              void* d_out, int out_size, void* d_ws, size_t ws_size,
                              hipStream_t stream) {
    const float* psrc  = (const float*)d_in[0];
    const float* pref  = (const float*)d_in[1];
    const float* beta  = (const float*)d_in[2];
    const float* alpha = (const float*)d_in[3];

    float* out     = (float*)d_out;
    float* outT    = out;            // (16,3,4)
    float* outPerm = out + 192;      // (16,1024,1024)
    float* ws      = (float*)d_ws;

    prep_kernel<<<PREP_FLOATS / 256, 256, 0, stream>>>(ws);

    void* args[] = { (void*)&psrc, (void*)&pref, (void*)&beta, (void*)&alpha,
                     (void*)&ws, (void*)&outT, (void*)&outPerm };
    hipError_t ce = hipLaunchCooperativeKernel((const void*)rpm_kernel,
                                               dim3(BATCH * BLK_PER_B), dim3(BLOCK_T),
                                               args, 0, stream);
    if (ce != hipSuccess) {
        rpm_kernel<<<dim3(BATCH * BLK_PER_B), dim3(BLOCK_T), 0, stream>>>(
            psrc, pref, beta, alpha, ws, outT, outPerm);
    }
}